// Round 1
// baseline (181.164 us; speedup 1.0000x reference)
//
#include <hip/hip_runtime.h>

// Problem constants (B=32, T=500, D=512)
constexpr int M_ROWS = 16000;   // B*T
constexpr int DIM    = 512;
constexpr int NEXP   = 10;      // routing experts
constexpr int NSH    = 5;       // shared experts
constexpr int KTOP   = 5;

// Tiling
constexpr int TM = 32;          // rows per block
constexpr int BK = 16;          // k-tile
constexpr int NP = DIM + 4;     // padded LDS stride for W1 tile (float4-aligned)
constexpr int GP = TM + 4;      // padded LDS stride for G tile

// 256 threads = 8 ty * 32 tx. Each thread: 4 rows (ty*4..+3) x 16 cols
// (cols = g*128 + tx*4 + j, g=0..3, j=0..3).
__global__ __launch_bounds__(256)
void moe_fused(const float* __restrict__ G,
               const float* __restrict__ value,
               const float* __restrict__ shared_w,
               const float* __restrict__ routing_w,
               const float* __restrict__ W1,
               const float* __restrict__ W2,
               float* __restrict__ out)
{
    __shared__ float W1s[BK][NP];
    __shared__ float Gs[BK][GP];

    const int tid  = threadIdx.x;
    const int tx   = tid & 31;
    const int ty   = tid >> 5;
    const int row0 = blockIdx.x * TM;
    const int r0   = ty * 4;

    float acc[4][16];
    #pragma unroll
    for (int r = 0; r < 4; ++r)
        #pragma unroll
        for (int c = 0; c < 16; ++c) acc[r][c] = 0.f;

    for (int k0 = 0; k0 < DIM; k0 += BK) {
        // Stage W1^T tile: W1s[kk][n] = W1[n][k0+kk]  (kk<16, n<512)
        #pragma unroll
        for (int i = 0; i < 8; ++i) {
            int c  = i * 256 + tid;      // 0..2047
            int n  = c & (DIM - 1);      // 0..511
            int kg = c >> 9;             // 0..3
            float4 v = *reinterpret_cast<const float4*>(&W1[(size_t)n * DIM + k0 + kg * 4]);
            W1s[kg * 4 + 0][n] = v.x;
            W1s[kg * 4 + 1][n] = v.y;
            W1s[kg * 4 + 2][n] = v.z;
            W1s[kg * 4 + 3][n] = v.w;
        }
        // Stage G tile: Gs[kk][m] = G[row0+m][k0+kk]
        if (tid < 128) {
            int m  = tid >> 2;           // 0..31
            int kg = tid & 3;            // 0..3
            float4 v = *reinterpret_cast<const float4*>(&G[(size_t)(row0 + m) * DIM + k0 + kg * 4]);
            Gs[kg * 4 + 0][m] = v.x;
            Gs[kg * 4 + 1][m] = v.y;
            Gs[kg * 4 + 2][m] = v.z;
            Gs[kg * 4 + 3][m] = v.w;
        }
        __syncthreads();

        #pragma unroll
        for (int kk = 0; kk < BK; ++kk) {
            float4 a4 = *reinterpret_cast<const float4*>(&Gs[kk][r0]);
            float a[4] = {a4.x, a4.y, a4.z, a4.w};
            float b[16];
            #pragma unroll
            for (int g = 0; g < 4; ++g) {
                float4 b4 = *reinterpret_cast<const float4*>(&W1s[kk][g * 128 + tx * 4]);
                b[g * 4 + 0] = b4.x; b[g * 4 + 1] = b4.y;
                b[g * 4 + 2] = b4.z; b[g * 4 + 3] = b4.w;
            }
            #pragma unroll
            for (int r = 0; r < 4; ++r)
                #pragma unroll
                for (int c = 0; c < 16; ++c)
                    acc[r][c] = fmaf(a[r], b[c], acc[r][c]);
        }
        __syncthreads();
    }

    // ReLU (h values; only needed for logits)
    #pragma unroll
    for (int r = 0; r < 4; ++r)
        #pragma unroll
        for (int c = 0; c < 16; ++c) acc[r][c] = fmaxf(acc[r][c], 0.f);

    // Per-thread logit partials over its 16 cols, then butterfly-reduce
    // across the 32 tx lanes (lane%32 group of the wave).
    float logit[4][NEXP];
    #pragma unroll
    for (int e = 0; e < NEXP; ++e) {
        float w2v[16];
        #pragma unroll
        for (int g = 0; g < 4; ++g) {
            float4 v = *reinterpret_cast<const float4*>(&W2[(size_t)e * DIM + g * 128 + tx * 4]);
            w2v[g * 4 + 0] = v.x; w2v[g * 4 + 1] = v.y;
            w2v[g * 4 + 2] = v.z; w2v[g * 4 + 3] = v.w;
        }
        #pragma unroll
        for (int r = 0; r < 4; ++r) {
            float s = 0.f;
            #pragma unroll
            for (int c = 0; c < 16; ++c) s = fmaf(acc[r][c], w2v[c], s);
            logit[r][e] = s;
        }
    }
    #pragma unroll
    for (int r = 0; r < 4; ++r)
        #pragma unroll
        for (int e = 0; e < NEXP; ++e) {
            float v = logit[r][e];
            #pragma unroll
            for (int m = 16; m >= 1; m >>= 1)
                v += __shfl_xor(v, m, 64);   // masks <32: stays in tx group
            logit[r][e] = v;
        }

    // Softmax + top-5 (redundant across tx lanes; all deterministic).
    float swv[4][NEXP];
    float valr[4];
    #pragma unroll
    for (int r = 0; r < 4; ++r) {
        float mx = logit[r][0];
        #pragma unroll
        for (int e = 1; e < NEXP; ++e) mx = fmaxf(mx, logit[r][e]);
        float p[NEXP];
        float se = 0.f;
        #pragma unroll
        for (int e = 0; e < NEXP; ++e) { p[e] = expf(logit[r][e] - mx); se += p[e]; }
        float inv = 1.f / se;
        #pragma unroll
        for (int e = 0; e < NEXP; ++e) p[e] *= inv;

        // top-5 via 5 strict-> argmax passes (ties -> lowest index, matches lax.top_k)
        unsigned used = 0;
        #pragma unroll
        for (int t = 0; t < KTOP; ++t) {
            float bv = -1.f; int bi = 0;
            #pragma unroll
            for (int e = 0; e < NEXP; ++e) {
                bool better = (((used >> e) & 1u) == 0u) && (p[e] > bv);
                bv = better ? p[e] : bv;
                bi = better ? e   : bi;
            }
            used |= 1u << bi;
        }
        #pragma unroll
        for (int e = 0; e < NEXP; ++e)
            swv[r][e] = ((used >> e) & 1u) ? p[e] : 0.f;

        valr[r] = value[row0 + r0 + r];
    }

    // Output: out[row][col] = value[row] * (sum_s shared_w[s][col]
    //                                       + sum_e swv[e]*routing_w[e][col])
    #pragma unroll
    for (int g = 0; g < 4; ++g) {
        int col = g * 128 + tx * 4;
        float4 sh = make_float4(0.f, 0.f, 0.f, 0.f);
        #pragma unroll
        for (int s = 0; s < NSH; ++s) {
            float4 v = *reinterpret_cast<const float4*>(&shared_w[(size_t)s * DIM + col]);
            sh.x += v.x; sh.y += v.y; sh.z += v.z; sh.w += v.w;
        }
        float4 rwv[NEXP];
        #pragma unroll
        for (int e = 0; e < NEXP; ++e)
            rwv[e] = *reinterpret_cast<const float4*>(&routing_w[(size_t)e * DIM + col]);
        #pragma unroll
        for (int r = 0; r < 4; ++r) {
            float4 o = sh;
            #pragma unroll
            for (int e = 0; e < NEXP; ++e) {
                float w = swv[r][e];
                o.x = fmaf(w, rwv[e].x, o.x);
                o.y = fmaf(w, rwv[e].y, o.y);
                o.z = fmaf(w, rwv[e].z, o.z);
                o.w = fmaf(w, rwv[e].w, o.w);
            }
            float v = valr[r];
            o.x *= v; o.y *= v; o.z *= v; o.w *= v;
            *reinterpret_cast<float4*>(&out[(size_t)(row0 + r0 + r) * DIM + col]) = o;
        }
    }
}

extern "C" void kernel_launch(void* const* d_in, const int* in_sizes, int n_in,
                              void* d_out, int out_size, void* d_ws, size_t ws_size,
                              hipStream_t stream) {
    const float* G         = (const float*)d_in[0];  // [B,T,D]
    const float* value     = (const float*)d_in[1];  // [B,T]
    const float* shared_w  = (const float*)d_in[2];  // [5,D]
    const float* routing_w = (const float*)d_in[3];  // [10,D]
    const float* W1        = (const float*)d_in[4];  // [D,D]
    const float* W2        = (const float*)d_in[5];  // [10,D]
    float* out             = (float*)d_out;          // [B,T,D] fp32

    dim3 grid(M_ROWS / TM);   // 500 blocks
    dim3 block(256);
    moe_fused<<<grid, block, 0, stream>>>(G, value, shared_w, routing_w, W1, W2, out);
}

// Round 2
// 69.044 us; speedup vs baseline: 2.6239x; 2.6239x over previous
//
#include <hip/hip_runtime.h>

constexpr int M_ROWS = 16000;   // B*T
constexpr int DIM    = 512;
constexpr int NEXP   = 10;
constexpr int NSH    = 5;
constexpr int KTOP   = 5;

constexpr int TM = 32;          // rows per block
constexpr int BK = 32;          // k-tile

typedef __attribute__((ext_vector_type(8))) short  bf16x8;   // 8 bf16 in 4 VGPRs
typedef __attribute__((ext_vector_type(4))) float  f32x4;

__device__ inline unsigned short bf16_rne(float x) {
    unsigned u = __float_as_uint(x);
    u += 0x7fffu + ((u >> 16) & 1u);
    return (unsigned short)(u >> 16);
}
__device__ inline float bf16_to_f(unsigned short h) {
    return __uint_as_float(((unsigned)h) << 16);
}

// ---------------- prep: W1 -> (hi,lo) bf16 [N][K]; shsum = sum_s shared_w ----
__global__ __launch_bounds__(256)
void prep_kernel(const float* __restrict__ W1, const float* __restrict__ shared_w,
                 unsigned short* __restrict__ w1hi, unsigned short* __restrict__ w1lo,
                 float* __restrict__ shsum)
{
    int b = blockIdx.x;
    if (b < 256) {
        int f = b * 256 + threadIdx.x;          // 0..65535, 4 floats each
        float4 v = *reinterpret_cast<const float4*>(&W1[(size_t)f * 4]);
        float xs[4] = {v.x, v.y, v.z, v.w};
        ushort4 h4, l4;
        unsigned short h[4], l[4];
        #pragma unroll
        for (int i = 0; i < 4; ++i) {
            h[i] = bf16_rne(xs[i]);
            float rem = xs[i] - bf16_to_f(h[i]);   // exact in fp32
            l[i] = bf16_rne(rem);
        }
        h4.x = h[0]; h4.y = h[1]; h4.z = h[2]; h4.w = h[3];
        l4.x = l[0]; l4.y = l[1]; l4.z = l[2]; l4.w = l[3];
        *reinterpret_cast<ushort4*>(&w1hi[(size_t)f * 4]) = h4;
        *reinterpret_cast<ushort4*>(&w1lo[(size_t)f * 4]) = l4;
    } else {
        for (int c = threadIdx.x; c < DIM; c += 256) {
            float s = 0.f;
            #pragma unroll
            for (int e = 0; e < NSH; ++e) s += shared_w[e * DIM + c];
            shsum[c] = s;
        }
    }
}

// ---------------- main fused kernel ----------------
// Block: 32 rows x 512 cols, 256 threads = 4 waves.
// Wave w: cols [w*128, w*128+128), 2 row-tiles x 8 col-tiles of 16x16x32 MFMA.
__global__ __launch_bounds__(256, 2)
void moe_mfma(const float* __restrict__ G, const float* __restrict__ value,
              const float* __restrict__ routing_w, const float* __restrict__ W2,
              const unsigned short* __restrict__ w1hi, const unsigned short* __restrict__ w1lo,
              const float* __restrict__ shsum, float* __restrict__ out)
{
    __shared__ unsigned short smem[34816];           // 69632 B
    unsigned short* Bhi = smem;                      // [512][32] bf16
    unsigned short* Blo = smem + 16384;              // [512][32]
    unsigned short* Ahi = smem + 32768;              // [32][32]
    unsigned short* Alo = smem + 33792;              // [32][32]

    const int tid  = threadIdx.x;
    const int lane = tid & 63;
    const int w    = tid >> 6;          // wave 0..3
    const int l15  = lane & 15;
    const int lg   = lane >> 4;         // 0..3
    const int row0 = blockIdx.x * TM;

    f32x4 acc[2][8];
    #pragma unroll
    for (int rt = 0; rt < 2; ++rt)
        #pragma unroll
        for (int ct = 0; ct < 8; ++ct) acc[rt][ct] = (f32x4)0.f;

    const int am = tid >> 3;            // 0..31 (A-stage row)
    const int aq = tid & 7;             // 0..7  (A-stage float4 slot)

    for (int k0 = 0; k0 < DIM; k0 += BK) {
        // ---- stage A (G rows): fp32 -> hi/lo bf16 in regs -> LDS
        float4 g4 = *reinterpret_cast<const float4*>(&G[(size_t)(row0 + am) * DIM + k0 + aq * 4]);
        {
            float xs[4] = {g4.x, g4.y, g4.z, g4.w};
            ushort4 h4, l4;
            unsigned short h[4], l[4];
            #pragma unroll
            for (int i = 0; i < 4; ++i) {
                h[i] = bf16_rne(xs[i]);
                float rem = xs[i] - bf16_to_f(h[i]);
                l[i] = bf16_rne(rem);
            }
            h4.x = h[0]; h4.y = h[1]; h4.z = h[2]; h4.w = h[3];
            l4.x = l[0]; l4.y = l[1]; l4.z = l[2]; l4.w = l[3];
            *reinterpret_cast<ushort4*>(&Ahi[am * 32 + aq * 4]) = h4;
            *reinterpret_cast<ushort4*>(&Alo[am * 32 + aq * 4]) = l4;
        }
        // ---- stage B (W1 hi/lo) via global_load_lds width-16, linear LDS
        #pragma unroll
        for (int r = 0; r < 8; ++r) {
            int f = r * 256 + tid;       // 0..2047
            int n = f >> 2;              // 0..511
            int j = f & 3;               // 16B chunk within row
            __builtin_amdgcn_global_load_lds(
                (const __attribute__((address_space(1))) void*)(w1hi + (size_t)n * DIM + k0 + j * 8),
                (__attribute__((address_space(3))) void*)(Bhi + f * 8),
                16, 0, 0);
        }
        #pragma unroll
        for (int r = 0; r < 8; ++r) {
            int f = r * 256 + tid;
            int n = f >> 2;
            int j = f & 3;
            __builtin_amdgcn_global_load_lds(
                (const __attribute__((address_space(1))) void*)(w1lo + (size_t)n * DIM + k0 + j * 8),
                (__attribute__((address_space(3))) void*)(Blo + f * 8),
                16, 0, 0);
        }
        __syncthreads();

        // ---- MFMA phase
        bf16x8 ah[2], al[2];
        ah[0] = *reinterpret_cast<const bf16x8*>(&Ahi[(l15)      * 32 + lg * 8]);
        ah[1] = *reinterpret_cast<const bf16x8*>(&Ahi[(16 + l15) * 32 + lg * 8]);
        al[0] = *reinterpret_cast<const bf16x8*>(&Alo[(l15)      * 32 + lg * 8]);
        al[1] = *reinterpret_cast<const bf16x8*>(&Alo[(16 + l15) * 32 + lg * 8]);
        #pragma unroll
        for (int ct = 0; ct < 8; ++ct) {
            int n = w * 128 + ct * 16 + l15;
            bf16x8 bh = *reinterpret_cast<const bf16x8*>(&Bhi[n * 32 + lg * 8]);
            bf16x8 bl = *reinterpret_cast<const bf16x8*>(&Blo[n * 32 + lg * 8]);
            acc[0][ct] = __builtin_amdgcn_mfma_f32_16x16x32_bf16(ah[0], bh, acc[0][ct], 0, 0, 0);
            acc[0][ct] = __builtin_amdgcn_mfma_f32_16x16x32_bf16(ah[0], bl, acc[0][ct], 0, 0, 0);
            acc[0][ct] = __builtin_amdgcn_mfma_f32_16x16x32_bf16(al[0], bh, acc[0][ct], 0, 0, 0);
            acc[1][ct] = __builtin_amdgcn_mfma_f32_16x16x32_bf16(ah[1], bh, acc[1][ct], 0, 0, 0);
            acc[1][ct] = __builtin_amdgcn_mfma_f32_16x16x32_bf16(ah[1], bl, acc[1][ct], 0, 0, 0);
            acc[1][ct] = __builtin_amdgcn_mfma_f32_16x16x32_bf16(al[1], bh, acc[1][ct], 0, 0, 0);
        }
        __syncthreads();
    }

    // ---- ReLU
    #pragma unroll
    for (int rt = 0; rt < 2; ++rt)
        #pragma unroll
        for (int ct = 0; ct < 8; ++ct)
            #pragma unroll
            for (int j = 0; j < 4; ++j)
                acc[rt][ct][j] = fmaxf(acc[rt][ct][j], 0.f);

    // ---- partial logits per wave -> LDS (reuse smem; last barrier already passed)
    float* plog = reinterpret_cast<float*>(smem);    // [4][32][10]
    float* swls = plog + 4 * TM * NEXP;              // [32][10]
    const int cb = w * 128;

    #pragma unroll
    for (int e = 0; e < NEXP; ++e) {
        float w2v[8];
        #pragma unroll
        for (int ct = 0; ct < 8; ++ct)
            w2v[ct] = W2[(size_t)e * DIM + cb + ct * 16 + l15];
        #pragma unroll
        for (int rt = 0; rt < 2; ++rt) {
            #pragma unroll
            for (int j = 0; j < 4; ++j) {
                float s = 0.f;
                #pragma unroll
                for (int ct = 0; ct < 8; ++ct)
                    s = fmaf(acc[rt][ct][j], w2v[ct], s);
                s += __shfl_xor(s, 1, 16);
                s += __shfl_xor(s, 2, 16);
                s += __shfl_xor(s, 4, 16);
                s += __shfl_xor(s, 8, 16);
                if (l15 == 0) {
                    int row = rt * 16 + lg * 4 + j;
                    plog[(w * TM + row) * NEXP + e] = s;
                }
            }
        }
    }
    __syncthreads();

    // ---- softmax + top-5 (one thread per row)
    if (tid < TM) {
        float lgt[NEXP];
        #pragma unroll
        for (int e = 0; e < NEXP; ++e)
            lgt[e] = plog[(0 * TM + tid) * NEXP + e] + plog[(1 * TM + tid) * NEXP + e]
                   + plog[(2 * TM + tid) * NEXP + e] + plog[(3 * TM + tid) * NEXP + e];
        float mx = lgt[0];
        #pragma unroll
        for (int e = 1; e < NEXP; ++e) mx = fmaxf(mx, lgt[e]);
        float p[NEXP], se = 0.f;
        #pragma unroll
        for (int e = 0; e < NEXP; ++e) { p[e] = expf(lgt[e] - mx); se += p[e]; }
        float inv = 1.f / se;
        #pragma unroll
        for (int e = 0; e < NEXP; ++e) p[e] *= inv;
        unsigned used = 0;
        #pragma unroll
        for (int t = 0; t < KTOP; ++t) {
            float bv = -1.f; int bi = 0;
            #pragma unroll
            for (int e = 0; e < NEXP; ++e) {
                bool better = (((used >> e) & 1u) == 0u) && (p[e] > bv);
                bv = better ? p[e] : bv;
                bi = better ? e : bi;
            }
            used |= 1u << bi;
        }
        #pragma unroll
        for (int e = 0; e < NEXP; ++e)
            swls[tid * NEXP + e] = ((used >> e) & 1u) ? p[e] : 0.f;
    }
    __syncthreads();

    // ---- output: out[row][col] = value[row]*(shsum[col] + sum_e sw[e]*rw[e][col])
    const int c4 = (tid & 127) * 4;
    const int rh = tid >> 7;                       // 0/1 -> rows rh*16..+15
    float4 sh4 = *reinterpret_cast<const float4*>(&shsum[c4]);
    float4 rw4[NEXP];
    #pragma unroll
    for (int e = 0; e < NEXP; ++e)
        rw4[e] = *reinterpret_cast<const float4*>(&routing_w[(size_t)e * DIM + c4]);
    #pragma unroll
    for (int r = 0; r < 16; ++r) {
        int row = rh * 16 + r;
        float val = value[row0 + row];
        float4 o = sh4;
        #pragma unroll
        for (int e = 0; e < NEXP; ++e) {
            float wgt = swls[row * NEXP + e];
            o.x = fmaf(wgt, rw4[e].x, o.x);
            o.y = fmaf(wgt, rw4[e].y, o.y);
            o.z = fmaf(wgt, rw4[e].z, o.z);
            o.w = fmaf(wgt, rw4[e].w, o.w);
        }
        o.x *= val; o.y *= val; o.z *= val; o.w *= val;
        *reinterpret_cast<float4*>(&out[(size_t)(row0 + row) * DIM + c4]) = o;
    }
}

extern "C" void kernel_launch(void* const* d_in, const int* in_sizes, int n_in,
                              void* d_out, int out_size, void* d_ws, size_t ws_size,
                              hipStream_t stream) {
    const float* G         = (const float*)d_in[0];
    const float* value     = (const float*)d_in[1];
    const float* shared_w  = (const float*)d_in[2];
    const float* routing_w = (const float*)d_in[3];
    const float* W1        = (const float*)d_in[4];
    const float* W2        = (const float*)d_in[5];
    float* out             = (float*)d_out;

    unsigned short* w1hi = (unsigned short*)d_ws;                       // 512 KB
    unsigned short* w1lo = (unsigned short*)((char*)d_ws + 524288);     // 512 KB
    float*          shs  = (float*)((char*)d_ws + 1048576);             // 2 KB

    prep_kernel<<<257, 256, 0, stream>>>(W1, shared_w, w1hi, w1lo, shs);
    moe_mfma<<<M_ROWS / TM, 256, 0, stream>>>(G, value, routing_w, W2,
                                              w1hi, w1lo, shs, out);
}